// Round 6
// baseline (287.542 us; speedup 1.0000x reference)
//
#include <hip/hip_runtime.h>
#include <math.h>

#define Bb 64
#define Dd 4096
#define Hh 32
#define Kk 128
#define Vv 128
#define Mm 4096
#define MC 4097
#define NCH 8            // flash m-chunks (512 m each, 8 subtiles of 64)
#define NSLOT 9          // 8 chunks + new-token slot

// workspace layout (float offsets)
#define WS_K1P  0                              // k1 partials: 34*16*8192
#define WS_Q    4456448                        // 262144
#define WS_NEWK (WS_Q + Bb*Hh*Kk)
#define WS_NEWV (WS_NEWK + Bb*Kk)
#define WS_PM   (WS_NEWV + Bb*Vv)              // 64*9*32
#define WS_PL   (WS_PM + Bb*NSLOT*Hh)
#define WS_PO   (WS_PL + Bb*NSLOT*Hh)          // 64*9*32*128
#define WS_O    (WS_PO + Bb*NSLOT*Hh*Vv)       // 262144
#define WS_YP   (WS_O + Bb*Hh*Vv)              // 8*262144

#define YSLOT (Bb*Dd)

// d_out layout (float offsets): y, Kc, Vc
#define OUT_Y  0
#define OUT_KC (Bb*Dd)
#define OUT_VC (OUT_KC + Bb*MC*Kk)

// ---------------- K1A: partial projections over d-chunk of 256
__global__ __launch_bounds__(256) void k1A_proj(const float* __restrict__ x,
        const float* __restrict__ Pq, const float* __restrict__ Pk,
        const float* __restrict__ Pv, float* __restrict__ part) {
    const int hidx = blockIdx.x;
    const int d0c  = blockIdx.y * 256;
    const int t = threadIdx.x;
    const int kg = t & 15, bg = t >> 4;
    const int kd = kg * 4, b0 = bg * 4;

    const float* P;
    if (hidx < Hh)       P = Pq + (size_t)hidx * Dd * Kk;
    else if (hidx == Hh) P = Pk;
    else                 P = Pv;

    __shared__ float xs[32 * 65];
    __shared__ float ps[32 * 128];

    float acc[4][8];
    #pragma unroll
    for (int a = 0; a < 4; a++)
        #pragma unroll
        for (int c = 0; c < 8; c++) acc[a][c] = 0.f;

    for (int tt = 0; tt < 8; tt++) {
        const int d0 = d0c + tt * 32;
        #pragma unroll
        for (int ii = 0; ii < 8; ii++) {
            int f = ii * 256 + t;
            int i = f & 31, bb = f >> 5;
            xs[i * 65 + bb] = x[(size_t)bb * Dd + d0 + i];
        }
        #pragma unroll
        for (int ii = 0; ii < 4; ii++) {
            int f = ii * 256 + t;
            int i = f >> 5, k4 = (f & 31) * 4;
            *(float4*)&ps[i * 128 + k4] = *(const float4*)&P[(size_t)(d0 + i) * Kk + k4];
        }
        __syncthreads();
        #pragma unroll
        for (int i = 0; i < 32; i++) {
            float xb[4];
            #pragma unroll
            for (int a = 0; a < 4; a++) xb[a] = xs[i * 65 + b0 + a];
            float4 p0 = *(float4*)&ps[i * 128 + kd];
            float4 p1 = *(float4*)&ps[i * 128 + 64 + kd];
            float pp[8] = {p0.x, p0.y, p0.z, p0.w, p1.x, p1.y, p1.z, p1.w};
            #pragma unroll
            for (int a = 0; a < 4; a++)
                #pragma unroll
                for (int c = 0; c < 8; c++)
                    acc[a][c] = fmaf(xb[a], pp[c], acc[a][c]);
        }
        __syncthreads();
    }
    float* dst = part + ((size_t)hidx * 16 + blockIdx.y) * 8192;
    #pragma unroll
    for (int a = 0; a < 4; a++) {
        int b = b0 + a;
        *(float4*)&dst[b * 128 + kd]      = make_float4(acc[a][0], acc[a][1], acc[a][2], acc[a][3]);
        *(float4*)&dst[b * 128 + 64 + kd] = make_float4(acc[a][4], acc[a][5], acc[a][6], acc[a][7]);
    }
}

// ---------------- K1B: reduce 16 chunks -> q / new_k / new_v
__global__ __launch_bounds__(256) void k1B_reduce(const float* __restrict__ part,
        float* __restrict__ ws) {
    const int o = blockIdx.x * 256 + threadIdx.x;
    const int hidx = o >> 13;
    const int rest = o & 8191;
    float s = 0.f;
    #pragma unroll
    for (int c = 0; c < 16; c++) s += part[((size_t)hidx * 16 + c) * 8192 + rest];
    if (hidx < Hh) {
        int b = rest >> 7, k = rest & 127;
        ws[WS_Q + ((size_t)b * Hh + hidx) * Kk + k] = s;
    } else if (hidx == Hh) {
        ws[WS_NEWK + rest] = s;
    } else {
        ws[WS_NEWV + rest] = s;
    }
}

// ---------------- KFLASH v3: outer-product QK^T / PV with register
// double-buffered K/V prefetch; fused Kc/Vc write-through.
// block 256 = (hg 0..15) x (lg 0..15); thread owns h = {2hg, 2hg+1}.
#define LOADKV(ST, KR, VR) { \
    const int m0_ = c * 512 + (ST) * 64; \
    _Pragma("unroll") \
    for (int ii = 0; ii < 4; ii++) { \
        int mm = mK + ii * 16; \
        const float* src = prevK + ((size_t)b * Mm + m0_ + mm) * Kk + kq * 4; \
        KR[ii]     = *(const float4*)src; \
        KR[ii + 4] = *(const float4*)(src + 64); \
    } \
    _Pragma("unroll") \
    for (int ii = 0; ii < 8; ii++) { \
        int mm = mV + ii * 8; \
        VR[ii] = *(const float4*)(prevV + ((size_t)b * Mm + m0_ + mm) * Vv + vq * 4); \
    } }

#define FLASH_BODY(KC, VC, KN, VN, ST, PRE) { \
    const int m0_ = c * 512 + (ST) * 64; \
    __syncthreads();                         /* A: LDS free from prior subtile */ \
    _Pragma("unroll") \
    for (int ii = 0; ii < 4; ii++) {         /* ds_write K half0 (transposed+ring) */ \
        int mm = mK + ii * 16; \
        int cs = (mm + 4 * kq) & 63; \
        ks_t[(kq*4+0)*64 + cs] = KC[ii].x; \
        ks_t[(kq*4+1)*64 + cs] = KC[ii].y; \
        ks_t[(kq*4+2)*64 + cs] = KC[ii].z; \
        ks_t[(kq*4+3)*64 + cs] = KC[ii].w; \
    } \
    _Pragma("unroll") \
    for (int ii = 0; ii < 8; ii++) {         /* ds_write V natural */ \
        int mm = mV + ii * 8; \
        *(float4*)&vs[mm * 132 + vq * 4] = VC[ii]; \
    } \
    __syncthreads();                         /* B: stage visible */ \
    if (PRE) LOADKV((ST) + 1, KN, VN);       /* prefetch next subtile */ \
    _Pragma("unroll") \
    for (int ii = 0; ii < 4; ii++) {         /* Kc write-through */ \
        int mm = mK + ii * 16; \
        float* dK = outKc + ((size_t)b * MC + m0_ + mm) * Kk + kq * 4; \
        *(float4*)dK        = KC[ii]; \
        *(float4*)(dK + 64) = KC[ii + 4]; \
    } \
    _Pragma("unroll") \
    for (int ii = 0; ii < 8; ii++) {         /* Vc write-through */ \
        int mm = mV + ii * 8; \
        *(float4*)(outVc + ((size_t)b * MC + m0_ + mm) * Vv + vq * 4) = VC[ii]; \
    } \
    float s[2][4] = {{0.f,0.f,0.f,0.f},{0.f,0.f,0.f,0.f}}; \
    _Pragma("unroll 4") \
    for (int k = 0; k < 64; k++) {           /* QK-0 */ \
        float2 q2 = *(float2*)&qs[k * 34 + h2]; \
        float4 k4 = *(float4*)&ks_t[k * 64 + ((4*lg + 4*(k>>2)) & 63)]; \
        s[0][0] = fmaf(q2.x, k4.x, s[0][0]); s[0][1] = fmaf(q2.x, k4.y, s[0][1]); \
        s[0][2] = fmaf(q2.x, k4.z, s[0][2]); s[0][3] = fmaf(q2.x, k4.w, s[0][3]); \
        s[1][0] = fmaf(q2.y, k4.x, s[1][0]); s[1][1] = fmaf(q2.y, k4.y, s[1][1]); \
        s[1][2] = fmaf(q2.y, k4.z, s[1][2]); s[1][3] = fmaf(q2.y, k4.w, s[1][3]); \
    } \
    __syncthreads();                         /* C: QK-0 readers done */ \
    _Pragma("unroll") \
    for (int ii = 0; ii < 4; ii++) {         /* ds_write K half1 */ \
        int mm = mK + ii * 16; \
        int cs = (mm + 4 * kq) & 63; \
        ks_t[(kq*4+0)*64 + cs] = KC[ii+4].x; \
        ks_t[(kq*4+1)*64 + cs] = KC[ii+4].y; \
        ks_t[(kq*4+2)*64 + cs] = KC[ii+4].z; \
        ks_t[(kq*4+3)*64 + cs] = KC[ii+4].w; \
    } \
    __syncthreads();                         /* D: K half1 ready */ \
    _Pragma("unroll 4") \
    for (int k = 0; k < 64; k++) {           /* QK-1 */ \
        float2 q2 = *(float2*)&qs[(64 + k) * 34 + h2]; \
        float4 k4 = *(float4*)&ks_t[k * 64 + ((4*lg + 4*(k>>2)) & 63)]; \
        s[0][0] = fmaf(q2.x, k4.x, s[0][0]); s[0][1] = fmaf(q2.x, k4.y, s[0][1]); \
        s[0][2] = fmaf(q2.x, k4.z, s[0][2]); s[0][3] = fmaf(q2.x, k4.w, s[0][3]); \
        s[1][0] = fmaf(q2.y, k4.x, s[1][0]); s[1][1] = fmaf(q2.y, k4.y, s[1][1]); \
        s[1][2] = fmaf(q2.y, k4.z, s[1][2]); s[1][3] = fmaf(q2.y, k4.w, s[1][3]); \
    } \
    float al[2]; \
    _Pragma("unroll") \
    for (int a = 0; a < 2; a++) {            /* register online softmax */ \
        float mloc = fmaxf(fmaxf(s[a][0], s[a][1]), fmaxf(s[a][2], s[a][3])); \
        mloc = fmaxf(mloc, __shfl_xor(mloc, 1, 64)); \
        mloc = fmaxf(mloc, __shfl_xor(mloc, 2, 64)); \
        mloc = fmaxf(mloc, __shfl_xor(mloc, 4, 64)); \
        mloc = fmaxf(mloc, __shfl_xor(mloc, 8, 64)); \
        float nm = fmaxf(rm[a], mloc); \
        al[a] = __expf(rm[a] - nm); \
        float psum = 0.f; \
        _Pragma("unroll") \
        for (int cc = 0; cc < 4; cc++) { \
            float p = __expf(s[a][cc] - nm); \
            wl_t[(4*lg + cc) * 36 + h2 + a] = p; \
            psum += p; \
        } \
        psum += __shfl_xor(psum, 1, 64); \
        psum += __shfl_xor(psum, 2, 64); \
        psum += __shfl_xor(psum, 4, 64); \
        psum += __shfl_xor(psum, 8, 64); \
        rl[a] = rl[a] * al[a] + psum; \
        rm[a] = nm; \
    } \
    _Pragma("unroll") \
    for (int a = 0; a < 2; a++) \
        _Pragma("unroll") \
        for (int j = 0; j < 8; j++) accO[a][j] *= al[a]; \
    for (int mm = 0; mm < 64; mm++) {        /* PV */ \
        float2 w2 = *(float2*)&wl_t[mm * 36 + h2]; \
        float4 v0 = *(float4*)&vs[mm * 132 + 4 * lg]; \
        float4 v1 = *(float4*)&vs[mm * 132 + 64 + 4 * lg]; \
        accO[0][0] = fmaf(w2.x, v0.x, accO[0][0]); \
        accO[0][1] = fmaf(w2.x, v0.y, accO[0][1]); \
        accO[0][2] = fmaf(w2.x, v0.z, accO[0][2]); \
        accO[0][3] = fmaf(w2.x, v0.w, accO[0][3]); \
        accO[0][4] = fmaf(w2.x, v1.x, accO[0][4]); \
        accO[0][5] = fmaf(w2.x, v1.y, accO[0][5]); \
        accO[0][6] = fmaf(w2.x, v1.z, accO[0][6]); \
        accO[0][7] = fmaf(w2.x, v1.w, accO[0][7]); \
        accO[1][0] = fmaf(w2.y, v0.x, accO[1][0]); \
        accO[1][1] = fmaf(w2.y, v0.y, accO[1][1]); \
        accO[1][2] = fmaf(w2.y, v0.z, accO[1][2]); \
        accO[1][3] = fmaf(w2.y, v0.w, accO[1][3]); \
        accO[1][4] = fmaf(w2.y, v1.x, accO[1][4]); \
        accO[1][5] = fmaf(w2.y, v1.y, accO[1][5]); \
        accO[1][6] = fmaf(w2.y, v1.z, accO[1][6]); \
        accO[1][7] = fmaf(w2.y, v1.w, accO[1][7]); \
    } }

__global__ __launch_bounds__(256, 2) void kflash(const float* __restrict__ prevK,
        const float* __restrict__ prevV, const float* __restrict__ wq,
        float* __restrict__ outKc, float* __restrict__ outVc,
        float* __restrict__ PM, float* __restrict__ PL, float* __restrict__ PO) {
    const int c = blockIdx.x;      // 0..7
    const int b = blockIdx.y;
    const int t = threadIdx.x;
    const int hg = t >> 4, lg = t & 15;
    const int h2 = hg * 2;
    const int kq = t & 15;
    const int mK = t >> 4;
    const int vq = t & 31;
    const int mV = t >> 5;

    __shared__ float ks_t[64 * 64];   // [k_half][m], ring-swizzled
    __shared__ float vs[64 * 132];    // [m][v], natural
    __shared__ float qs[128 * 34];    // [k][h]
    __shared__ float wl_t[64 * 36];   // [m][h]

    float4 ka[8], va[8], kb[8], vb[8];
    LOADKV(0, ka, va);

    // stage q once (block-wide): 32h x 128k (visible after barrier B of subtile 0)
    {
        const int h = t >> 3, kc = t & 7;
        const float* qr = wq + ((size_t)b * Hh + h) * Kk + kc * 16;
        float4 a0 = *(const float4*)&qr[0];
        float4 a1 = *(const float4*)&qr[4];
        float4 a2 = *(const float4*)&qr[8];
        float4 a3 = *(const float4*)&qr[12];
        const int k0 = kc * 16;
        qs[(k0+ 0)*34 + h] = a0.x; qs[(k0+ 1)*34 + h] = a0.y;
        qs[(k0+ 2)*34 + h] = a0.z; qs[(k0+ 3)*34 + h] = a0.w;
        qs[(k0+ 4)*34 + h] = a1.x; qs[(k0+ 5)*34 + h] = a1.y;
        qs[(k0+ 6)*34 + h] = a1.z; qs[(k0+ 7)*34 + h] = a1.w;
        qs[(k0+ 8)*34 + h] = a2.x; qs[(k0+ 9)*34 + h] = a2.y;
        qs[(k0+10)*34 + h] = a2.z; qs[(k0+11)*34 + h] = a2.w;
        qs[(k0+12)*34 + h] = a3.x; qs[(k0+13)*34 + h] = a3.y;
        qs[(k0+14)*34 + h] = a3.z; qs[(k0+15)*34 + h] = a3.w;
    }

    float rm[2] = {-3.0e38f, -3.0e38f};
    float rl[2] = {0.f, 0.f};
    float accO[2][8] = {};

    FLASH_BODY(ka, va, kb, vb, 0, true)
    FLASH_BODY(kb, vb, ka, va, 1, true)
    FLASH_BODY(ka, va, kb, vb, 2, true)
    FLASH_BODY(kb, vb, ka, va, 3, true)
    FLASH_BODY(ka, va, kb, vb, 4, true)
    FLASH_BODY(kb, vb, ka, va, 5, true)
    FLASH_BODY(ka, va, kb, vb, 6, true)
    FLASH_BODY(kb, vb, ka, va, 7, false)

    // write partials
    const size_t base = ((size_t)b * NSLOT + c) * Hh;
    if (lg == 0) {
        PM[base + h2]     = rm[0];
        PM[base + h2 + 1] = rm[1];
        PL[base + h2]     = rl[0];
        PL[base + h2 + 1] = rl[1];
    }
    #pragma unroll
    for (int a = 0; a < 2; a++) {
        float* po = PO + (base + h2 + a) * Vv;
        *(float4*)&po[4*lg]      = make_float4(accO[a][0], accO[a][1], accO[a][2], accO[a][3]);
        *(float4*)&po[64 + 4*lg] = make_float4(accO[a][4], accO[a][5], accO[a][6], accO[a][7]);
    }
}

// ---------------- KNEW: new-token slot NCH partial + Kc/Vc row 4096
__global__ __launch_bounds__(128) void knew(const float* __restrict__ ws,
        float* __restrict__ outKc, float* __restrict__ outVc,
        float* __restrict__ PM, float* __restrict__ PL, float* __restrict__ PO) {
    const int b = blockIdx.x, t = threadIdx.x;
    const float* q    = ws + WS_Q;
    const float* newk = ws + WS_NEWK;
    const float* newv = ws + WS_NEWV;
    const int h = t >> 2, j = t & 3;
    const float* qr = q + ((size_t)b * Hh + h) * Kk + j * 32;
    const float* nk = newk + (size_t)b * Kk + j * 32;
    float s0 = 0.f, s1 = 0.f, s2 = 0.f, s3 = 0.f;
    #pragma unroll
    for (int i = 0; i < 8; i++) {
        float4 a  = *(const float4*)&qr[i * 4];
        float4 c4 = *(const float4*)&nk[i * 4];
        s0 = fmaf(a.x, c4.x, s0); s1 = fmaf(a.y, c4.y, s1);
        s2 = fmaf(a.z, c4.z, s2); s3 = fmaf(a.w, c4.w, s3);
    }
    float s = (s0 + s1) + (s2 + s3);
    s += __shfl_xor(s, 1, 64);
    s += __shfl_xor(s, 2, 64);
    const size_t base = ((size_t)b * NSLOT + NCH) * Hh;
    if (j == 0) { PM[base + h] = s; PL[base + h] = 1.f; }
    float nv = newv[(size_t)b * Vv + t];
    outKc[((size_t)b * MC + Mm) * Kk + t] = newk[(size_t)b * Kk + t];
    outVc[((size_t)b * MC + Mm) * Vv + t] = nv;
    #pragma unroll 4
    for (int hh = 0; hh < Hh; hh++)
        PO[(base + hh) * Vv + t] = nv;
}

// ---------------- KCOMB: merge NSLOT partial slots -> O[b,h,v]
__global__ __launch_bounds__(128) void kcomb(const float* __restrict__ PM,
        const float* __restrict__ PL, const float* __restrict__ PO,
        float* __restrict__ O) {
    const int h = blockIdx.x, b = blockIdx.y, t = threadIdx.x;
    __shared__ float ml[NSLOT], ll[NSLOT];
    if (t < NSLOT) {
        ml[t] = PM[((size_t)b * NSLOT + t) * Hh + h];
        ll[t] = PL[((size_t)b * NSLOT + t) * Hh + h];
    }
    __syncthreads();
    float M = -3.0e38f;
    #pragma unroll
    for (int c = 0; c < NSLOT; c++) M = fmaxf(M, ml[c]);
    float L = 0.f, o = 0.f;
    #pragma unroll
    for (int c = 0; c < NSLOT; c++) {
        float e = __expf(ml[c] - M);
        L += ll[c] * e;
        o = fmaf(e, PO[(((size_t)b * NSLOT + c) * Hh + h) * Vv + t], o);
    }
    O[((size_t)b * Hh + h) * Vv + t] = o / L;
}

// ---------------- K5: y_part[hq][b,d] = sum_{h in quad, v} O[b,h,v] * P_o[h,d,v]
__global__ __launch_bounds__(256) void k5_outproj(const float* __restrict__ O,
        const float* __restrict__ Po, float* __restrict__ ypart) {
    const int dbase = blockIdx.x * 64;
    const int hq = blockIdx.y;
    const int t = threadIdx.x;
    __shared__ float os[64 * 64];   // [b][v-half], ring-swizzled
    __shared__ float ps2[64 * 64];  // [d][v-half], ring-swizzled
    const int dg = t & 15, bg = t >> 4;
    const int d0 = dg * 4, b0 = bg * 4;
    float acc[4][4] = {};
    for (int hi = 0; hi < 4; hi++) {
        const int h = hq * 4 + hi;
        for (int vh = 0; vh < 2; vh++) {
            __syncthreads();
            #pragma unroll
            for (int ii = 0; ii < 4; ii++) {
                int f = ii * 256 + t;
                int vq2 = f & 15, r = f >> 4;
                int colp = (4 * vq2 + 4 * (r >> 2)) & 63;
                *(float4*)&os[r * 64 + colp] =
                    *(const float4*)&O[((size_t)(r * Hh + h)) * Vv + vh * 64 + 4 * vq2];
                *(float4*)&ps2[r * 64 + colp] =
                    *(const float4*)&Po[((size_t)h * Dd + dbase + r) * Vv + vh * 64 + 4 * vq2];
            }
            __syncthreads();
            #pragma unroll
            for (int v4 = 0; v4 < 16; v4++) {
                float4 pd[4], ob[4];
                #pragma unroll
                for (int cc = 0; cc < 4; cc++)
                    pd[cc] = *(float4*)&ps2[(d0 + cc) * 64 + ((4*v4 + 4*dg) & 63)];
                #pragma unroll
                for (int a = 0; a < 4; a++)
                    ob[a] = *(float4*)&os[(b0 + a) * 64 + ((4*v4 + 4*bg) & 63)];
                #pragma unroll
                for (int a = 0; a < 4; a++)
                    #pragma unroll
                    for (int cc = 0; cc < 4; cc++) {
                        acc[a][cc] = fmaf(ob[a].x, pd[cc].x, acc[a][cc]);
                        acc[a][cc] = fmaf(ob[a].y, pd[cc].y, acc[a][cc]);
                        acc[a][cc] = fmaf(ob[a].z, pd[cc].z, acc[a][cc]);
                        acc[a][cc] = fmaf(ob[a].w, pd[cc].w, acc[a][cc]);
                    }
            }
        }
    }
    float* yp = ypart + (size_t)hq * YSLOT;
    #pragma unroll
    for (int a = 0; a < 4; a++)
        *(float4*)&yp[(size_t)(b0 + a) * Dd + dbase + d0] =
            make_float4(acc[a][0], acc[a][1], acc[a][2], acc[a][3]);
}

// ---------------- K5r: y = sum of 8 y-partial slots
__global__ __launch_bounds__(256) void k5r_yreduce(const float* __restrict__ ypart,
        float* __restrict__ y) {
    const int o = blockIdx.x * 256 + threadIdx.x;
    float s = 0.f;
    #pragma unroll
    for (int c = 0; c < 8; c++) s += ypart[(size_t)c * YSLOT + o];
    y[o] = s;
}

extern "C" void kernel_launch(void* const* d_in, const int* in_sizes, int n_in,
                              void* d_out, int out_size, void* d_ws, size_t ws_size,
                              hipStream_t stream) {
    const float* x     = (const float*)d_in[0];
    const float* prevK = (const float*)d_in[1];
    const float* prevV = (const float*)d_in[2];
    const float* Pq    = (const float*)d_in[3];
    const float* Pk    = (const float*)d_in[4];
    const float* Pv    = (const float*)d_in[5];
    const float* Po    = (const float*)d_in[6];
    float* out = (float*)d_out;
    float* ws  = (float*)d_ws;

    k1A_proj<<<dim3(Hh + 2, 16), 256, 0, stream>>>(x, Pq, Pk, Pv, ws + WS_K1P);
    k1B_reduce<<<(34 * 8192) / 256, 256, 0, stream>>>(ws + WS_K1P, ws);
    kflash<<<dim3(NCH, Bb), 256, 0, stream>>>(prevK, prevV, ws + WS_Q,
                                              out + OUT_KC, out + OUT_VC,
                                              ws + WS_PM, ws + WS_PL, ws + WS_PO);
    knew<<<Bb, 128, 0, stream>>>(ws, out + OUT_KC, out + OUT_VC,
                                 ws + WS_PM, ws + WS_PL, ws + WS_PO);
    kcomb<<<dim3(Hh, Bb), 128, 0, stream>>>(ws + WS_PM, ws + WS_PL, ws + WS_PO,
                                            ws + WS_O);
    k5_outproj<<<dim3(64, 8), 256, 0, stream>>>(ws + WS_O, Po, ws + WS_YP);
    k5r_yreduce<<<YSLOT / 256, 256, 0, stream>>>(ws + WS_YP, out + OUT_Y);
}

// Round 7
// 285.527 us; speedup vs baseline: 1.0071x; 1.0071x over previous
//
#include <hip/hip_runtime.h>
#include <math.h>

#define Bb 64
#define Dd 4096
#define Hh 32
#define Kk 128
#define Vv 128
#define Mm 4096
#define MC 4097
#define NCH 16           // flash m-chunks (256 m each)
#define NSLOT 17         // 16 chunks + new-token slot

// workspace layout (float offsets)
#define WS_K1P  0                              // k1 partials: 34*16*8192
#define WS_Q    4456448                        // 262144
#define WS_NEWK (WS_Q + Bb*Hh*Kk)
#define WS_NEWV (WS_NEWK + Bb*Kk)
#define WS_PM   (WS_NEWV + Bb*Vv)              // 64*17*32
#define WS_PL   (WS_PM + Bb*NSLOT*Hh)
#define WS_PO   (WS_PL + Bb*NSLOT*Hh)          // 64*17*32*128
#define WS_O    (WS_PO + Bb*NSLOT*Hh*Vv)       // 262144
#define WS_YP   (WS_O + Bb*Hh*Vv)              // 8*262144

#define YSLOT (Bb*Dd)

// d_out layout (float offsets): y, Kc, Vc
#define OUT_Y  0
#define OUT_KC (Bb*Dd)
#define OUT_VC (OUT_KC + Bb*MC*Kk)

// ---------------- K1A: partial projections over d-chunk of 256
__global__ __launch_bounds__(256) void k1A_proj(const float* __restrict__ x,
        const float* __restrict__ Pq, const float* __restrict__ Pk,
        const float* __restrict__ Pv, float* __restrict__ part) {
    const int hidx = blockIdx.x;
    const int d0c  = blockIdx.y * 256;
    const int t = threadIdx.x;
    const int kg = t & 15, bg = t >> 4;
    const int kd = kg * 4, b0 = bg * 4;

    const float* P;
    if (hidx < Hh)       P = Pq + (size_t)hidx * Dd * Kk;
    else if (hidx == Hh) P = Pk;
    else                 P = Pv;

    __shared__ float xs[32 * 65];
    __shared__ float ps[32 * 128];

    float acc[4][8];
    #pragma unroll
    for (int a = 0; a < 4; a++)
        #pragma unroll
        for (int c = 0; c < 8; c++) acc[a][c] = 0.f;

    for (int tt = 0; tt < 8; tt++) {
        const int d0 = d0c + tt * 32;
        #pragma unroll
        for (int ii = 0; ii < 8; ii++) {
            int f = ii * 256 + t;
            int i = f & 31, bb = f >> 5;
            xs[i * 65 + bb] = x[(size_t)bb * Dd + d0 + i];
        }
        #pragma unroll
        for (int ii = 0; ii < 4; ii++) {
            int f = ii * 256 + t;
            int i = f >> 5, k4 = (f & 31) * 4;
            *(float4*)&ps[i * 128 + k4] = *(const float4*)&P[(size_t)(d0 + i) * Kk + k4];
        }
        __syncthreads();
        #pragma unroll
        for (int i = 0; i < 32; i++) {
            float xb[4];
            #pragma unroll
            for (int a = 0; a < 4; a++) xb[a] = xs[i * 65 + b0 + a];
            float4 p0 = *(float4*)&ps[i * 128 + kd];
            float4 p1 = *(float4*)&ps[i * 128 + 64 + kd];
            float pp[8] = {p0.x, p0.y, p0.z, p0.w, p1.x, p1.y, p1.z, p1.w};
            #pragma unroll
            for (int a = 0; a < 4; a++)
                #pragma unroll
                for (int c = 0; c < 8; c++)
                    acc[a][c] = fmaf(xb[a], pp[c], acc[a][c]);
        }
        __syncthreads();
    }
    float* dst = part + ((size_t)hidx * 16 + blockIdx.y) * 8192;
    #pragma unroll
    for (int a = 0; a < 4; a++) {
        int b = b0 + a;
        *(float4*)&dst[b * 128 + kd]      = make_float4(acc[a][0], acc[a][1], acc[a][2], acc[a][3]);
        *(float4*)&dst[b * 128 + 64 + kd] = make_float4(acc[a][4], acc[a][5], acc[a][6], acc[a][7]);
    }
}

// ---------------- K1B: reduce 16 chunks -> q / new_k / new_v
__global__ __launch_bounds__(256) void k1B_reduce(const float* __restrict__ part,
        float* __restrict__ ws) {
    const int o = blockIdx.x * 256 + threadIdx.x;
    const int hidx = o >> 13;
    const int rest = o & 8191;
    float s = 0.f;
    #pragma unroll
    for (int c = 0; c < 16; c++) s += part[((size_t)hidx * 16 + c) * 8192 + rest];
    if (hidx < Hh) {
        int b = rest >> 7, k = rest & 127;
        ws[WS_Q + ((size_t)b * Hh + hidx) * Kk + k] = s;
    } else if (hidx == Hh) {
        ws[WS_NEWK + rest] = s;
    } else {
        ws[WS_NEWV + rest] = s;
    }
}

// ---------------- KFLASH v5: v2 math/tiling, quarter-K + half-V staging for
// 50.5 KB LDS -> 3 blocks/CU occupancy. No register prefetch (regressed).
// block 256 = (hg 0..15) x (lg 0..15); thread owns h = {2hg, 2hg+1}.

// write one 32-k quarter of K (transposed + ring swizzle); SEL picks kq half,
// OFF picks ka[0..3] (k 0..63) vs ka[4..7] (k 64..127)
#define WRITEK(SEL, OFF) { \
    if ((kq >> 3) == (SEL)) { \
        const int kq7 = kq & 7; \
        _Pragma("unroll") \
        for (int ii = 0; ii < 4; ii++) { \
            int mm = mK + ii * 16; \
            int cs = (mm + 4 * kq7) & 63; \
            ks_t[(4*kq7+0)*64 + cs] = ka[ii+(OFF)].x; \
            ks_t[(4*kq7+1)*64 + cs] = ka[ii+(OFF)].y; \
            ks_t[(4*kq7+2)*64 + cs] = ka[ii+(OFF)].z; \
            ks_t[(4*kq7+3)*64 + cs] = ka[ii+(OFF)].w; \
        } \
    } }

// QK over one staged 32-k quarter; KB = global k base of the quarter
#define QKQ(KB) { \
    _Pragma("unroll 8") \
    for (int r = 0; r < 32; r++) { \
        float2 q2 = *(float2*)&qs[((KB) + r) * 34 + h2]; \
        float4 k4 = *(float4*)&ks_t[r * 64 + ((4*lg + 4*(r>>2)) & 63)]; \
        s[0][0] = fmaf(q2.x, k4.x, s[0][0]); s[0][1] = fmaf(q2.x, k4.y, s[0][1]); \
        s[0][2] = fmaf(q2.x, k4.z, s[0][2]); s[0][3] = fmaf(q2.x, k4.w, s[0][3]); \
        s[1][0] = fmaf(q2.y, k4.x, s[1][0]); s[1][1] = fmaf(q2.y, k4.y, s[1][1]); \
        s[1][2] = fmaf(q2.y, k4.z, s[1][2]); s[1][3] = fmaf(q2.y, k4.w, s[1][3]); \
    } }

// PV over one staged 32-m half; MB = wl row base (global m within subtile)
#define PVH(MB) { \
    _Pragma("unroll 4") \
    for (int mm = 0; mm < 32; mm++) { \
        float2 w2 = *(float2*)&wl_t[((MB) + mm) * 36 + h2]; \
        float4 v0 = *(float4*)&vs[mm * 132 + 4 * lg]; \
        float4 v1 = *(float4*)&vs[mm * 132 + 64 + 4 * lg]; \
        accO[0][0] = fmaf(w2.x, v0.x, accO[0][0]); \
        accO[0][1] = fmaf(w2.x, v0.y, accO[0][1]); \
        accO[0][2] = fmaf(w2.x, v0.z, accO[0][2]); \
        accO[0][3] = fmaf(w2.x, v0.w, accO[0][3]); \
        accO[0][4] = fmaf(w2.x, v1.x, accO[0][4]); \
        accO[0][5] = fmaf(w2.x, v1.y, accO[0][5]); \
        accO[0][6] = fmaf(w2.x, v1.z, accO[0][6]); \
        accO[0][7] = fmaf(w2.x, v1.w, accO[0][7]); \
        accO[1][0] = fmaf(w2.y, v0.x, accO[1][0]); \
        accO[1][1] = fmaf(w2.y, v0.y, accO[1][1]); \
        accO[1][2] = fmaf(w2.y, v0.z, accO[1][2]); \
        accO[1][3] = fmaf(w2.y, v0.w, accO[1][3]); \
        accO[1][4] = fmaf(w2.y, v1.x, accO[1][4]); \
        accO[1][5] = fmaf(w2.y, v1.y, accO[1][5]); \
        accO[1][6] = fmaf(w2.y, v1.z, accO[1][6]); \
        accO[1][7] = fmaf(w2.y, v1.w, accO[1][7]); \
    } }

__global__ __launch_bounds__(256, 3) void kflash(const float* __restrict__ prevK,
        const float* __restrict__ prevV, const float* __restrict__ wq,
        float* __restrict__ outKc, float* __restrict__ outVc,
        float* __restrict__ PM, float* __restrict__ PL, float* __restrict__ PO) {
    const int c = blockIdx.x;      // 0..15
    const int b = blockIdx.y;
    const int t = threadIdx.x;
    const int hg = t >> 4, lg = t & 15;
    const int h2 = hg * 2;
    const int kq = t & 15;
    const int mK = t >> 4;
    const int vq = t & 31;
    const int mV = t >> 5;

    __shared__ float ks_t[32 * 64];   // [k_quarter][m], ring-swizzled (8 KB)
    __shared__ float vs[32 * 132];    // [m_half][v], natural (16.9 KB)
    __shared__ float qs[128 * 34];    // [k][h] (17.4 KB)
    __shared__ float wl_t[64 * 36];   // [m][h] (9.2 KB)

    // ---- stage q once (block-wide): 32h x 128k
    {
        const int h = t >> 3, kc = t & 7;
        const float* qr = wq + ((size_t)b * Hh + h) * Kk + kc * 16;
        float4 a0 = *(const float4*)&qr[0];
        float4 a1 = *(const float4*)&qr[4];
        float4 a2 = *(const float4*)&qr[8];
        float4 a3 = *(const float4*)&qr[12];
        const int k0 = kc * 16;
        qs[(k0+ 0)*34 + h] = a0.x; qs[(k0+ 1)*34 + h] = a0.y;
        qs[(k0+ 2)*34 + h] = a0.z; qs[(k0+ 3)*34 + h] = a0.w;
        qs[(k0+ 4)*34 + h] = a1.x; qs[(k0+ 5)*34 + h] = a1.y;
        qs[(k0+ 6)*34 + h] = a1.z; qs[(k0+ 7)*34 + h] = a1.w;
        qs[(k0+ 8)*34 + h] = a2.x; qs[(k0+ 9)*34 + h] = a2.y;
        qs[(k0+10)*34 + h] = a2.z; qs[(k0+11)*34 + h] = a2.w;
        qs[(k0+12)*34 + h] = a3.x; qs[(k0+13)*34 + h] = a3.y;
        qs[(k0+14)*34 + h] = a3.z; qs[(k0+15)*34 + h] = a3.w;
    }

    float rm[2] = {-3.0e38f, -3.0e38f};
    float rl[2] = {0.f, 0.f};
    float accO[2][8] = {};

    for (int st = 0; st < 4; st++) {
        const int m0 = c * 256 + st * 64;
        __syncthreads();                                  // S1: prior readers done
        // ---- global loads (blocking, v2 style)
        float4 ka[8], va[8];
        #pragma unroll
        for (int ii = 0; ii < 4; ii++) {
            int mm = mK + ii * 16;
            const float* src = prevK + ((size_t)b * Mm + m0 + mm) * Kk + kq * 4;
            ka[ii]     = *(const float4*)src;
            ka[ii + 4] = *(const float4*)(src + 64);
        }
        #pragma unroll
        for (int ii = 0; ii < 8; ii++) {
            int mm = mV + ii * 8;
            va[ii] = *(const float4*)(prevV + ((size_t)b * Mm + m0 + mm) * Vv + vq * 4);
        }
        // ---- stage V half0 (m 0..31) + K quarter0 (k 0..31)
        #pragma unroll
        for (int ii = 0; ii < 4; ii++)
            *(float4*)&vs[(mV + ii * 8) * 132 + vq * 4] = va[ii];
        WRITEK(0, 0)
        __syncthreads();                                  // S2
        // ---- write-through cache copies (drain under QK)
        #pragma unroll
        for (int ii = 0; ii < 4; ii++) {
            int mm = mK + ii * 16;
            float* dK = outKc + ((size_t)b * MC + m0 + mm) * Kk + kq * 4;
            *(float4*)dK        = ka[ii];
            *(float4*)(dK + 64) = ka[ii + 4];
        }
        #pragma unroll
        for (int ii = 0; ii < 8; ii++) {
            int mm = mV + ii * 8;
            *(float4*)(outVc + ((size_t)b * MC + m0 + mm) * Vv + vq * 4) = va[ii];
        }
        float s[2][4] = {{0.f,0.f,0.f,0.f},{0.f,0.f,0.f,0.f}};
        QKQ(0)
        __syncthreads();                                  // S3
        WRITEK(1, 0)                                      // k 32..63
        __syncthreads();                                  // S4
        QKQ(32)
        __syncthreads();                                  // S5
        WRITEK(0, 4)                                      // k 64..95
        __syncthreads();                                  // S6
        QKQ(64)
        __syncthreads();                                  // S7
        WRITEK(1, 4)                                      // k 96..127
        __syncthreads();                                  // S8
        QKQ(96)
        // ---- register online softmax (per-thread, redundant across lg)
        float al[2];
        #pragma unroll
        for (int a = 0; a < 2; a++) {
            float mloc = fmaxf(fmaxf(s[a][0], s[a][1]), fmaxf(s[a][2], s[a][3]));
            mloc = fmaxf(mloc, __shfl_xor(mloc, 1, 64));
            mloc = fmaxf(mloc, __shfl_xor(mloc, 2, 64));
            mloc = fmaxf(mloc, __shfl_xor(mloc, 4, 64));
            mloc = fmaxf(mloc, __shfl_xor(mloc, 8, 64));
            float nm = fmaxf(rm[a], mloc);
            al[a] = __expf(rm[a] - nm);
            float psum = 0.f;
            #pragma unroll
            for (int cc = 0; cc < 4; cc++) {
                float p = __expf(s[a][cc] - nm);
                wl_t[(4*lg + cc) * 36 + h2 + a] = p;
                psum += p;
            }
            psum += __shfl_xor(psum, 1, 64);
            psum += __shfl_xor(psum, 2, 64);
            psum += __shfl_xor(psum, 4, 64);
            psum += __shfl_xor(psum, 8, 64);
            rl[a] = rl[a] * al[a] + psum;
            rm[a] = nm;
        }
        #pragma unroll
        for (int a = 0; a < 2; a++)
            #pragma unroll
            for (int j = 0; j < 8; j++) accO[a][j] *= al[a];
        // ---- PV half0 (wl same-wave; vs half0 staged pre-S2)
        PVH(0)
        __syncthreads();                                  // S9
        #pragma unroll
        for (int ii = 0; ii < 4; ii++)                    // stage V half1 (m 32..63)
            *(float4*)&vs[(mV + ii * 8) * 132 + vq * 4] = va[ii + 4];
        __syncthreads();                                  // S10
        PVH(32)
    }
    // write partials
    const size_t base = ((size_t)b * NSLOT + c) * Hh;
    if (lg == 0) {
        PM[base + h2]     = rm[0];
        PM[base + h2 + 1] = rm[1];
        PL[base + h2]     = rl[0];
        PL[base + h2 + 1] = rl[1];
    }
    #pragma unroll
    for (int a = 0; a < 2; a++) {
        float* po = PO + (base + h2 + a) * Vv;
        *(float4*)&po[4*lg]      = make_float4(accO[a][0], accO[a][1], accO[a][2], accO[a][3]);
        *(float4*)&po[64 + 4*lg] = make_float4(accO[a][4], accO[a][5], accO[a][6], accO[a][7]);
    }
}

// ---------------- KNEW: new-token slot NCH partial + Kc/Vc row 4096
__global__ __launch_bounds__(128) void knew(const float* __restrict__ ws,
        float* __restrict__ outKc, float* __restrict__ outVc,
        float* __restrict__ PM, float* __restrict__ PL, float* __restrict__ PO) {
    const int b = blockIdx.x, t = threadIdx.x;
    const float* q    = ws + WS_Q;
    const float* newk = ws + WS_NEWK;
    const float* newv = ws + WS_NEWV;
    const int h = t >> 2, j = t & 3;
    const float* qr = q + ((size_t)b * Hh + h) * Kk + j * 32;
    const float* nk = newk + (size_t)b * Kk + j * 32;
    float s0 = 0.f, s1 = 0.f, s2 = 0.f, s3 = 0.f;
    #pragma unroll
    for (int i = 0; i < 8; i++) {
        float4 a  = *(const float4*)&qr[i * 4];
        float4 c4 = *(const float4*)&nk[i * 4];
        s0 = fmaf(a.x, c4.x, s0); s1 = fmaf(a.y, c4.y, s1);
        s2 = fmaf(a.z, c4.z, s2); s3 = fmaf(a.w, c4.w, s3);
    }
    float s = (s0 + s1) + (s2 + s3);
    s += __shfl_xor(s, 1, 64);
    s += __shfl_xor(s, 2, 64);
    const size_t base = ((size_t)b * NSLOT + NCH) * Hh;
    if (j == 0) { PM[base + h] = s; PL[base + h] = 1.f; }
    float nv = newv[(size_t)b * Vv + t];
    outKc[((size_t)b * MC + Mm) * Kk + t] = newk[(size_t)b * Kk + t];
    outVc[((size_t)b * MC + Mm) * Vv + t] = nv;
    #pragma unroll 4
    for (int hh = 0; hh < Hh; hh++)
        PO[(base + hh) * Vv + t] = nv;
}

// ---------------- KCOMB: merge NSLOT partial slots -> O[b,h,v]
__global__ __launch_bounds__(128) void kcomb(const float* __restrict__ PM,
        const float* __restrict__ PL, const float* __restrict__ PO,
        float* __restrict__ O) {
    const int h = blockIdx.x, b = blockIdx.y, t = threadIdx.x;
    __shared__ float ml[NSLOT], ll[NSLOT];
    if (t < NSLOT) {
        ml[t] = PM[((size_t)b * NSLOT + t) * Hh + h];
        ll[t] = PL[((size_t)b * NSLOT + t) * Hh + h];
    }
    __syncthreads();
    float M = -3.0e38f;
    #pragma unroll
    for (int c = 0; c < NSLOT; c++) M = fmaxf(M, ml[c]);
    float L = 0.f, o = 0.f;
    #pragma unroll
    for (int c = 0; c < NSLOT; c++) {
        float e = __expf(ml[c] - M);
        L += ll[c] * e;
        o = fmaf(e, PO[(((size_t)b * NSLOT + c) * Hh + h) * Vv + t], o);
    }
    O[((size_t)b * Hh + h) * Vv + t] = o / L;
}

// ---------------- K5: y_part[hq][b,d] = sum_{h in quad, v} O[b,h,v] * P_o[h,d,v]
__global__ __launch_bounds__(256) void k5_outproj(const float* __restrict__ O,
        const float* __restrict__ Po, float* __restrict__ ypart) {
    const int dbase = blockIdx.x * 64;
    const int hq = blockIdx.y;
    const int t = threadIdx.x;
    __shared__ float os[64 * 64];   // [b][v-half], ring-swizzled
    __shared__ float ps2[64 * 64];  // [d][v-half], ring-swizzled
    const int dg = t & 15, bg = t >> 4;
    const int d0 = dg * 4, b0 = bg * 4;
    float acc[4][4] = {};
    for (int hi = 0; hi < 4; hi++) {
        const int h = hq * 4 + hi;
        for (int vh = 0; vh < 2; vh++) {
            __syncthreads();
            #pragma unroll
            for (int ii = 0; ii < 4; ii++) {
                int f = ii * 256 + t;
                int vq2 = f & 15, r = f >> 4;
                int colp = (4 * vq2 + 4 * (r >> 2)) & 63;
                *(float4*)&os[r * 64 + colp] =
                    *(const float4*)&O[((size_t)(r * Hh + h)) * Vv + vh * 64 + 4 * vq2];
                *(float4*)&ps2[r * 64 + colp] =
                    *(const float4*)&Po[((size_t)h * Dd + dbase + r) * Vv + vh * 64 + 4 * vq2];
            }
            __syncthreads();
            #pragma unroll
            for (int v4 = 0; v4 < 16; v4++) {
                float4 pd[4], ob[4];
                #pragma unroll
                for (int cc = 0; cc < 4; cc++)
                    pd[cc] = *(float4*)&ps2[(d0 + cc) * 64 + ((4*v4 + 4*dg) & 63)];
                #pragma unroll
                for (int a = 0; a < 4; a++)
                    ob[a] = *(float4*)&os[(b0 + a) * 64 + ((4*v4 + 4*bg) & 63)];
                #pragma unroll
                for (int a = 0; a < 4; a++)
                    #pragma unroll
                    for (int cc = 0; cc < 4; cc++) {
                        acc[a][cc] = fmaf(ob[a].x, pd[cc].x, acc[a][cc]);
                        acc[a][cc] = fmaf(ob[a].y, pd[cc].y, acc[a][cc]);
                        acc[a][cc] = fmaf(ob[a].z, pd[cc].z, acc[a][cc]);
                        acc[a][cc] = fmaf(ob[a].w, pd[cc].w, acc[a][cc]);
                    }
            }
        }
    }
    float* yp = ypart + (size_t)hq * YSLOT;
    #pragma unroll
    for (int a = 0; a < 4; a++)
        *(float4*)&yp[(size_t)(b0 + a) * Dd + dbase + d0] =
            make_float4(acc[a][0], acc[a][1], acc[a][2], acc[a][3]);
}

// ---------------- K5r: y = sum of 8 y-partial slots
__global__ __launch_bounds__(256) void k5r_yreduce(const float* __restrict__ ypart,
        float* __restrict__ y) {
    const int o = blockIdx.x * 256 + threadIdx.x;
    float s = 0.f;
    #pragma unroll
    for (int c = 0; c < 8; c++) s += ypart[(size_t)c * YSLOT + o];
    y[o] = s;
}

extern "C" void kernel_launch(void* const* d_in, const int* in_sizes, int n_in,
                              void* d_out, int out_size, void* d_ws, size_t ws_size,
                              hipStream_t stream) {
    const float* x     = (const float*)d_in[0];
    const float* prevK = (const float*)d_in[1];
    const float* prevV = (const float*)d_in[2];
    const float* Pq    = (const float*)d_in[3];
    const float* Pk    = (const float*)d_in[4];
    const float* Pv    = (const float*)d_in[5];
    const float* Po    = (const float*)d_in[6];
    float* out = (float*)d_out;
    float* ws  = (float*)d_ws;

    k1A_proj<<<dim3(Hh + 2, 16), 256, 0, stream>>>(x, Pq, Pk, Pv, ws + WS_K1P);
    k1B_reduce<<<(34 * 8192) / 256, 256, 0, stream>>>(ws + WS_K1P, ws);
    kflash<<<dim3(NCH, Bb), 256, 0, stream>>>(prevK, prevV, ws + WS_Q,
                                              out + OUT_KC, out + OUT_VC,
                                              ws + WS_PM, ws + WS_PL, ws + WS_PO);
    knew<<<Bb, 128, 0, stream>>>(ws, out + OUT_KC, out + OUT_VC,
                                 ws + WS_PM, ws + WS_PL, ws + WS_PO);
    kcomb<<<dim3(Hh, Bb), 128, 0, stream>>>(ws + WS_PM, ws + WS_PL, ws + WS_PO,
                                            ws + WS_O);
    k5_outproj<<<dim3(64, 8), 256, 0, stream>>>(ws + WS_O, Po, ws + WS_YP);
    k5r_yreduce<<<YSLOT / 256, 256, 0, stream>>>(ws + WS_YP, out + OUT_Y);
}

// Round 8
// 273.066 us; speedup vs baseline: 1.0530x; 1.0456x over previous
//
#include <hip/hip_runtime.h>
#include <math.h>

#define Bb 64
#define Dd 4096
#define Hh 32
#define Kk 128
#define Vv 128
#define Mm 4096
#define MC 4097
#define NCH 16           // flash m-chunks (256 m each)
#define NSLOT 17         // 16 chunks + new-token slot

// workspace layout (float offsets)
#define WS_K1P  0                              // k1 partials: 34*16*8192
#define WS_Q    4456448                        // 262144
#define WS_NEWK (WS_Q + Bb*Hh*Kk)
#define WS_NEWV (WS_NEWK + Bb*Kk)
#define WS_PM   (WS_NEWV + Bb*Vv)              // 64*17*32
#define WS_PL   (WS_PM + Bb*NSLOT*Hh)
#define WS_PO   (WS_PL + Bb*NSLOT*Hh)          // 64*17*32*128
#define WS_O    (WS_PO + Bb*NSLOT*Hh*Vv)       // 262144
#define WS_YP   (WS_O + Bb*Hh*Vv)              // 8*262144

#define YSLOT (Bb*Dd)

// d_out layout (float offsets): y, Kc, Vc
#define OUT_Y  0
#define OUT_KC (Bb*Dd)
#define OUT_VC (OUT_KC + Bb*MC*Kk)

// LDS-only barrier: does NOT drain vmcnt, so global stores / prefetch loads
// stay in flight across it (unlike __syncthreads, which emits vmcnt(0)).
#define BAR_LGKM() do { \
    __builtin_amdgcn_sched_barrier(0); \
    asm volatile("s_waitcnt lgkmcnt(0)" ::: "memory"); \
    __builtin_amdgcn_s_barrier(); \
    __builtin_amdgcn_sched_barrier(0); \
} while (0)

// ---------------- K1A: partial projections over d-chunk of 256
__global__ __launch_bounds__(256) void k1A_proj(const float* __restrict__ x,
        const float* __restrict__ Pq, const float* __restrict__ Pk,
        const float* __restrict__ Pv, float* __restrict__ part) {
    const int hidx = blockIdx.x;
    const int d0c  = blockIdx.y * 256;
    const int t = threadIdx.x;
    const int kg = t & 15, bg = t >> 4;
    const int kd = kg * 4, b0 = bg * 4;

    const float* P;
    if (hidx < Hh)       P = Pq + (size_t)hidx * Dd * Kk;
    else if (hidx == Hh) P = Pk;
    else                 P = Pv;

    __shared__ float xs[32 * 65];
    __shared__ float ps[32 * 128];

    float acc[4][8];
    #pragma unroll
    for (int a = 0; a < 4; a++)
        #pragma unroll
        for (int c = 0; c < 8; c++) acc[a][c] = 0.f;

    for (int tt = 0; tt < 8; tt++) {
        const int d0 = d0c + tt * 32;
        #pragma unroll
        for (int ii = 0; ii < 8; ii++) {
            int f = ii * 256 + t;
            int i = f & 31, bb = f >> 5;
            xs[i * 65 + bb] = x[(size_t)bb * Dd + d0 + i];
        }
        #pragma unroll
        for (int ii = 0; ii < 4; ii++) {
            int f = ii * 256 + t;
            int i = f >> 5, k4 = (f & 31) * 4;
            *(float4*)&ps[i * 128 + k4] = *(const float4*)&P[(size_t)(d0 + i) * Kk + k4];
        }
        __syncthreads();
        #pragma unroll
        for (int i = 0; i < 32; i++) {
            float xb[4];
            #pragma unroll
            for (int a = 0; a < 4; a++) xb[a] = xs[i * 65 + b0 + a];
            float4 p0 = *(float4*)&ps[i * 128 + kd];
            float4 p1 = *(float4*)&ps[i * 128 + 64 + kd];
            float pp[8] = {p0.x, p0.y, p0.z, p0.w, p1.x, p1.y, p1.z, p1.w};
            #pragma unroll
            for (int a = 0; a < 4; a++)
                #pragma unroll
                for (int c = 0; c < 8; c++)
                    acc[a][c] = fmaf(xb[a], pp[c], acc[a][c]);
        }
        __syncthreads();
    }
    float* dst = part + ((size_t)hidx * 16 + blockIdx.y) * 8192;
    #pragma unroll
    for (int a = 0; a < 4; a++) {
        int b = b0 + a;
        *(float4*)&dst[b * 128 + kd]      = make_float4(acc[a][0], acc[a][1], acc[a][2], acc[a][3]);
        *(float4*)&dst[b * 128 + 64 + kd] = make_float4(acc[a][4], acc[a][5], acc[a][6], acc[a][7]);
    }
}

// ---------------- K1B: reduce 16 chunks -> q / new_k / new_v
__global__ __launch_bounds__(256) void k1B_reduce(const float* __restrict__ part,
        float* __restrict__ ws) {
    const int o = blockIdx.x * 256 + threadIdx.x;
    const int hidx = o >> 13;
    const int rest = o & 8191;
    float s = 0.f;
    #pragma unroll
    for (int c = 0; c < 16; c++) s += part[((size_t)hidx * 16 + c) * 8192 + rest];
    if (hidx < Hh) {
        int b = rest >> 7, k = rest & 127;
        ws[WS_Q + ((size_t)b * Hh + hidx) * Kk + k] = s;
    } else if (hidx == Hh) {
        ws[WS_NEWK + rest] = s;
    } else {
        ws[WS_NEWV + rest] = s;
    }
}

// ---------------- KFLASH v6: v2 layouts + raw lgkm-only barriers +
// register double-buffered prefetch (loads/stores fly across barriers).
// block 256 = (hg 0..15) x (lg 0..15); thread owns h = {2hg, 2hg+1}.
#define LOADKV(ST, KR, VR) { \
    const int m0_ = c * 256 + (ST) * 64; \
    _Pragma("unroll") \
    for (int ii = 0; ii < 4; ii++) { \
        int mm = mK + ii * 16; \
        const float* src = prevK + ((size_t)b * Mm + m0_ + mm) * Kk + kq * 4; \
        KR[ii]     = *(const float4*)src; \
        KR[ii + 4] = *(const float4*)(src + 64); \
    } \
    _Pragma("unroll") \
    for (int ii = 0; ii < 8; ii++) { \
        int mm = mV + ii * 8; \
        VR[ii] = *(const float4*)(prevV + ((size_t)b * Mm + m0_ + mm) * Vv + vq * 4); \
    } }

#define FLASH_BODY(KC, VC, KN, VN, ST, PRE) { \
    const int m0_ = c * 256 + (ST) * 64; \
    BAR_LGKM();                              /* S1: prior readers consumed */ \
    _Pragma("unroll") \
    for (int ii = 0; ii < 4; ii++) {         /* ds_write K half0 (transposed+ring) */ \
        int mm = mK + ii * 16; \
        int cs = (mm + 4 * kq) & 63; \
        ks_t[(kq*4+0)*64 + cs] = KC[ii].x; \
        ks_t[(kq*4+1)*64 + cs] = KC[ii].y; \
        ks_t[(kq*4+2)*64 + cs] = KC[ii].z; \
        ks_t[(kq*4+3)*64 + cs] = KC[ii].w; \
    } \
    _Pragma("unroll") \
    for (int ii = 0; ii < 8; ii++) {         /* ds_write V natural */ \
        int mm = mV + ii * 8; \
        *(float4*)&vs[mm * 132 + vq * 4] = VC[ii]; \
    } \
    BAR_LGKM();                              /* S2: stage visible */ \
    if (PRE) LOADKV((ST) + 1, KN, VN);       /* prefetch; stays in flight */ \
    _Pragma("unroll") \
    for (int ii = 0; ii < 4; ii++) {         /* Kc write-through */ \
        int mm = mK + ii * 16; \
        float* dK = outKc + ((size_t)b * MC + m0_ + mm) * Kk + kq * 4; \
        *(float4*)dK        = KC[ii]; \
        *(float4*)(dK + 64) = KC[ii + 4]; \
    } \
    _Pragma("unroll") \
    for (int ii = 0; ii < 8; ii++) {         /* Vc write-through */ \
        int mm = mV + ii * 8; \
        *(float4*)(outVc + ((size_t)b * MC + m0_ + mm) * Vv + vq * 4) = VC[ii]; \
    } \
    float s[2][4] = {{0.f,0.f,0.f,0.f},{0.f,0.f,0.f,0.f}}; \
    _Pragma("unroll 4") \
    for (int k = 0; k < 64; k++) {           /* QK-0 */ \
        float2 q2 = *(float2*)&qs[k * 34 + h2]; \
        float4 k4 = *(float4*)&ks_t[k * 64 + ((4*lg + 4*(k>>2)) & 63)]; \
        s[0][0] = fmaf(q2.x, k4.x, s[0][0]); s[0][1] = fmaf(q2.x, k4.y, s[0][1]); \
        s[0][2] = fmaf(q2.x, k4.z, s[0][2]); s[0][3] = fmaf(q2.x, k4.w, s[0][3]); \
        s[1][0] = fmaf(q2.y, k4.x, s[1][0]); s[1][1] = fmaf(q2.y, k4.y, s[1][1]); \
        s[1][2] = fmaf(q2.y, k4.z, s[1][2]); s[1][3] = fmaf(q2.y, k4.w, s[1][3]); \
    } \
    BAR_LGKM();                              /* S3: QK-0 reads consumed */ \
    _Pragma("unroll") \
    for (int ii = 0; ii < 4; ii++) {         /* ds_write K half1 */ \
        int mm = mK + ii * 16; \
        int cs = (mm + 4 * kq) & 63; \
        ks_t[(kq*4+0)*64 + cs] = KC[ii+4].x; \
        ks_t[(kq*4+1)*64 + cs] = KC[ii+4].y; \
        ks_t[(kq*4+2)*64 + cs] = KC[ii+4].z; \
        ks_t[(kq*4+3)*64 + cs] = KC[ii+4].w; \
    } \
    BAR_LGKM();                              /* S4: K half1 ready */ \
    _Pragma("unroll 4") \
    for (int k = 0; k < 64; k++) {           /* QK-1 */ \
        float2 q2 = *(float2*)&qs[(64 + k) * 34 + h2]; \
        float4 k4 = *(float4*)&ks_t[k * 64 + ((4*lg + 4*(k>>2)) & 63)]; \
        s[0][0] = fmaf(q2.x, k4.x, s[0][0]); s[0][1] = fmaf(q2.x, k4.y, s[0][1]); \
        s[0][2] = fmaf(q2.x, k4.z, s[0][2]); s[0][3] = fmaf(q2.x, k4.w, s[0][3]); \
        s[1][0] = fmaf(q2.y, k4.x, s[1][0]); s[1][1] = fmaf(q2.y, k4.y, s[1][1]); \
        s[1][2] = fmaf(q2.y, k4.z, s[1][2]); s[1][3] = fmaf(q2.y, k4.w, s[1][3]); \
    } \
    float al[2]; \
    _Pragma("unroll") \
    for (int a = 0; a < 2; a++) {            /* register online softmax */ \
        float mloc = fmaxf(fmaxf(s[a][0], s[a][1]), fmaxf(s[a][2], s[a][3])); \
        mloc = fmaxf(mloc, __shfl_xor(mloc, 1, 64)); \
        mloc = fmaxf(mloc, __shfl_xor(mloc, 2, 64)); \
        mloc = fmaxf(mloc, __shfl_xor(mloc, 4, 64)); \
        mloc = fmaxf(mloc, __shfl_xor(mloc, 8, 64)); \
        float nm = fmaxf(rm[a], mloc); \
        al[a] = __expf(rm[a] - nm); \
        float psum = 0.f; \
        _Pragma("unroll") \
        for (int cc = 0; cc < 4; cc++) { \
            float p = __expf(s[a][cc] - nm); \
            wl_t[(4*lg + cc) * 36 + h2 + a] = p; \
            psum += p; \
        } \
        psum += __shfl_xor(psum, 1, 64); \
        psum += __shfl_xor(psum, 2, 64); \
        psum += __shfl_xor(psum, 4, 64); \
        psum += __shfl_xor(psum, 8, 64); \
        rl[a] = rl[a] * al[a] + psum; \
        rm[a] = nm; \
    } \
    _Pragma("unroll") \
    for (int a = 0; a < 2; a++) \
        _Pragma("unroll") \
        for (int j = 0; j < 8; j++) accO[a][j] *= al[a]; \
    for (int mm = 0; mm < 64; mm++) {        /* PV (wl_t same-wave RAW) */ \
        float2 w2 = *(float2*)&wl_t[mm * 36 + h2]; \
        float4 v0 = *(float4*)&vs[mm * 132 + 4 * lg]; \
        float4 v1 = *(float4*)&vs[mm * 132 + 64 + 4 * lg]; \
        accO[0][0] = fmaf(w2.x, v0.x, accO[0][0]); \
        accO[0][1] = fmaf(w2.x, v0.y, accO[0][1]); \
        accO[0][2] = fmaf(w2.x, v0.z, accO[0][2]); \
        accO[0][3] = fmaf(w2.x, v0.w, accO[0][3]); \
        accO[0][4] = fmaf(w2.x, v1.x, accO[0][4]); \
        accO[0][5] = fmaf(w2.x, v1.y, accO[0][5]); \
        accO[0][6] = fmaf(w2.x, v1.z, accO[0][6]); \
        accO[0][7] = fmaf(w2.x, v1.w, accO[0][7]); \
        accO[1][0] = fmaf(w2.y, v0.x, accO[1][0]); \
        accO[1][1] = fmaf(w2.y, v0.y, accO[1][1]); \
        accO[1][2] = fmaf(w2.y, v0.z, accO[1][2]); \
        accO[1][3] = fmaf(w2.y, v0.w, accO[1][3]); \
        accO[1][4] = fmaf(w2.y, v1.x, accO[1][4]); \
        accO[1][5] = fmaf(w2.y, v1.y, accO[1][5]); \
        accO[1][6] = fmaf(w2.y, v1.z, accO[1][6]); \
        accO[1][7] = fmaf(w2.y, v1.w, accO[1][7]); \
    } }

__global__ __launch_bounds__(256, 2) void kflash(const float* __restrict__ prevK,
        const float* __restrict__ prevV, const float* __restrict__ wq,
        float* __restrict__ outKc, float* __restrict__ outVc,
        float* __restrict__ PM, float* __restrict__ PL, float* __restrict__ PO) {
    const int c = blockIdx.x;      // 0..15
    const int b = blockIdx.y;
    const int t = threadIdx.x;
    const int hg = t >> 4, lg = t & 15;
    const int h2 = hg * 2;
    const int kq = t & 15;
    const int mK = t >> 4;
    const int vq = t & 31;
    const int mV = t >> 5;

    __shared__ float ks_t[64 * 64];   // [k_half][m], ring-swizzled
    __shared__ float vs[64 * 132];    // [m][v], natural
    __shared__ float qs[128 * 34];    // [k][h]
    __shared__ float wl_t[64 * 36];   // [m][h]

    float4 ka[8], va[8], kb[8], vb[8];
    LOADKV(0, ka, va);

    // stage q once (block-wide): visible after first BAR of subtile 0
    {
        const int h = t >> 3, kc = t & 7;
        const float* qr = wq + ((size_t)b * Hh + h) * Kk + kc * 16;
        float4 a0 = *(const float4*)&qr[0];
        float4 a1 = *(const float4*)&qr[4];
        float4 a2 = *(const float4*)&qr[8];
        float4 a3 = *(const float4*)&qr[12];
        const int k0 = kc * 16;
        qs[(k0+ 0)*34 + h] = a0.x; qs[(k0+ 1)*34 + h] = a0.y;
        qs[(k0+ 2)*34 + h] = a0.z; qs[(k0+ 3)*34 + h] = a0.w;
        qs[(k0+ 4)*34 + h] = a1.x; qs[(k0+ 5)*34 + h] = a1.y;
        qs[(k0+ 6)*34 + h] = a1.z; qs[(k0+ 7)*34 + h] = a1.w;
        qs[(k0+ 8)*34 + h] = a2.x; qs[(k0+ 9)*34 + h] = a2.y;
        qs[(k0+10)*34 + h] = a2.z; qs[(k0+11)*34 + h] = a2.w;
        qs[(k0+12)*34 + h] = a3.x; qs[(k0+13)*34 + h] = a3.y;
        qs[(k0+14)*34 + h] = a3.z; qs[(k0+15)*34 + h] = a3.w;
    }

    float rm[2] = {-3.0e38f, -3.0e38f};
    float rl[2] = {0.f, 0.f};
    float accO[2][8] = {};

    FLASH_BODY(ka, va, kb, vb, 0, true)
    FLASH_BODY(kb, vb, ka, va, 1, true)
    FLASH_BODY(ka, va, kb, vb, 2, true)
    FLASH_BODY(kb, vb, ka, va, 3, false)

    // write partials
    const size_t base = ((size_t)b * NSLOT + c) * Hh;
    if (lg == 0) {
        PM[base + h2]     = rm[0];
        PM[base + h2 + 1] = rm[1];
        PL[base + h2]     = rl[0];
        PL[base + h2 + 1] = rl[1];
    }
    #pragma unroll
    for (int a = 0; a < 2; a++) {
        float* po = PO + (base + h2 + a) * Vv;
        *(float4*)&po[4*lg]      = make_float4(accO[a][0], accO[a][1], accO[a][2], accO[a][3]);
        *(float4*)&po[64 + 4*lg] = make_float4(accO[a][4], accO[a][5], accO[a][6], accO[a][7]);
    }
}

// ---------------- KNEW: new-token slot NCH partial + Kc/Vc row 4096
__global__ __launch_bounds__(128) void knew(const float* __restrict__ ws,
        float* __restrict__ outKc, float* __restrict__ outVc,
        float* __restrict__ PM, float* __restrict__ PL, float* __restrict__ PO) {
    const int b = blockIdx.x, t = threadIdx.x;
    const float* q    = ws + WS_Q;
    const float* newk = ws + WS_NEWK;
    const float* newv = ws + WS_NEWV;
    const int h = t >> 2, j = t & 3;
    const float* qr = q + ((size_t)b * Hh + h) * Kk + j * 32;
    const float* nk = newk + (size_t)b * Kk + j * 32;
    float s0 = 0.f, s1 = 0.f, s2 = 0.f, s3 = 0.f;
    #pragma unroll
    for (int i = 0; i < 8; i++) {
        float4 a  = *(const float4*)&qr[i * 4];
        float4 c4 = *(const float4*)&nk[i * 4];
        s0 = fmaf(a.x, c4.x, s0); s1 = fmaf(a.y, c4.y, s1);
        s2 = fmaf(a.z, c4.z, s2); s3 = fmaf(a.w, c4.w, s3);
    }
    float s = (s0 + s1) + (s2 + s3);
    s += __shfl_xor(s, 1, 64);
    s += __shfl_xor(s, 2, 64);
    const size_t base = ((size_t)b * NSLOT + NCH) * Hh;
    if (j == 0) { PM[base + h] = s; PL[base + h] = 1.f; }
    float nv = newv[(size_t)b * Vv + t];
    outKc[((size_t)b * MC + Mm) * Kk + t] = newk[(size_t)b * Kk + t];
    outVc[((size_t)b * MC + Mm) * Vv + t] = nv;
    #pragma unroll 4
    for (int hh = 0; hh < Hh; hh++)
        PO[(base + hh) * Vv + t] = nv;
}

// ---------------- KCOMB: merge NSLOT partial slots -> O[b,h,v]
__global__ __launch_bounds__(128) void kcomb(const float* __restrict__ PM,
        const float* __restrict__ PL, const float* __restrict__ PO,
        float* __restrict__ O) {
    const int h = blockIdx.x, b = blockIdx.y, t = threadIdx.x;
    __shared__ float ml[NSLOT], ll[NSLOT];
    if (t < NSLOT) {
        ml[t] = PM[((size_t)b * NSLOT + t) * Hh + h];
        ll[t] = PL[((size_t)b * NSLOT + t) * Hh + h];
    }
    __syncthreads();
    float M = -3.0e38f;
    #pragma unroll
    for (int c = 0; c < NSLOT; c++) M = fmaxf(M, ml[c]);
    float L = 0.f, o = 0.f;
    #pragma unroll
    for (int c = 0; c < NSLOT; c++) {
        float e = __expf(ml[c] - M);
        L += ll[c] * e;
        o = fmaf(e, PO[(((size_t)b * NSLOT + c) * Hh + h) * Vv + t], o);
    }
    O[((size_t)b * Hh + h) * Vv + t] = o / L;
}

// ---------------- K5: y_part[hq][b,d] = sum_{h in quad, v} O[b,h,v] * P_o[h,d,v]
__global__ __launch_bounds__(256) void k5_outproj(const float* __restrict__ O,
        const float* __restrict__ Po, float* __restrict__ ypart) {
    const int dbase = blockIdx.x * 64;
    const int hq = blockIdx.y;
    const int t = threadIdx.x;
    __shared__ float os[64 * 64];   // [b][v-half], ring-swizzled
    __shared__ float ps2[64 * 64];  // [d][v-half], ring-swizzled
    const int dg = t & 15, bg = t >> 4;
    const int d0 = dg * 4, b0 = bg * 4;
    float acc[4][4] = {};
    for (int hi = 0; hi < 4; hi++) {
        const int h = hq * 4 + hi;
        for (int vh = 0; vh < 2; vh++) {
            __syncthreads();
            #pragma unroll
            for (int ii = 0; ii < 4; ii++) {
                int f = ii * 256 + t;
                int vq2 = f & 15, r = f >> 4;
                int colp = (4 * vq2 + 4 * (r >> 2)) & 63;
                *(float4*)&os[r * 64 + colp] =
                    *(const float4*)&O[((size_t)(r * Hh + h)) * Vv + vh * 64 + 4 * vq2];
                *(float4*)&ps2[r * 64 + colp] =
                    *(const float4*)&Po[((size_t)h * Dd + dbase + r) * Vv + vh * 64 + 4 * vq2];
            }
            __syncthreads();
            #pragma unroll
            for (int v4 = 0; v4 < 16; v4++) {
                float4 pd[4], ob[4];
                #pragma unroll
                for (int cc = 0; cc < 4; cc++)
                    pd[cc] = *(float4*)&ps2[(d0 + cc) * 64 + ((4*v4 + 4*dg) & 63)];
                #pragma unroll
                for (int a = 0; a < 4; a++)
                    ob[a] = *(float4*)&os[(b0 + a) * 64 + ((4*v4 + 4*bg) & 63)];
                #pragma unroll
                for (int a = 0; a < 4; a++)
                    #pragma unroll
                    for (int cc = 0; cc < 4; cc++) {
                        acc[a][cc] = fmaf(ob[a].x, pd[cc].x, acc[a][cc]);
                        acc[a][cc] = fmaf(ob[a].y, pd[cc].y, acc[a][cc]);
                        acc[a][cc] = fmaf(ob[a].z, pd[cc].z, acc[a][cc]);
                        acc[a][cc] = fmaf(ob[a].w, pd[cc].w, acc[a][cc]);
                    }
            }
        }
    }
    float* yp = ypart + (size_t)hq * YSLOT;
    #pragma unroll
    for (int a = 0; a < 4; a++)
        *(float4*)&yp[(size_t)(b0 + a) * Dd + dbase + d0] =
            make_float4(acc[a][0], acc[a][1], acc[a][2], acc[a][3]);
}

// ---------------- K5r: y = sum of 8 y-partial slots
__global__ __launch_bounds__(256) void k5r_yreduce(const float* __restrict__ ypart,
        float* __restrict__ y) {
    const int o = blockIdx.x * 256 + threadIdx.x;
    float s = 0.f;
    #pragma unroll
    for (int c = 0; c < 8; c++) s += ypart[(size_t)c * YSLOT + o];
    y[o] = s;
}

extern "C" void kernel_launch(void* const* d_in, const int* in_sizes, int n_in,
                              void* d_out, int out_size, void* d_ws, size_t ws_size,
                              hipStream_t stream) {
    const float* x     = (const float*)d_in[0];
    const float* prevK = (const float*)d_in[1];
    const float* prevV = (const float*)d_in[2];
    const float* Pq    = (const float*)d_in[3];
    const float* Pk    = (const float*)d_in[4];
    const float* Pv    = (const float*)d_in[5];
    const float* Po    = (const float*)d_in[6];
    float* out = (float*)d_out;
    float* ws  = (float*)d_ws;

    k1A_proj<<<dim3(Hh + 2, 16), 256, 0, stream>>>(x, Pq, Pk, Pv, ws + WS_K1P);
    k1B_reduce<<<(34 * 8192) / 256, 256, 0, stream>>>(ws + WS_K1P, ws);
    kflash<<<dim3(NCH, Bb), 256, 0, stream>>>(prevK, prevV, ws + WS_Q,
                                              out + OUT_KC, out + OUT_VC,
                                              ws + WS_PM, ws + WS_PL, ws + WS_PO);
    knew<<<Bb, 128, 0, stream>>>(ws, out + OUT_KC, out + OUT_VC,
                                 ws + WS_PM, ws + WS_PL, ws + WS_PO);
    kcomb<<<dim3(Hh, Bb), 128, 0, stream>>>(ws + WS_PM, ws + WS_PL, ws + WS_PO,
                                            ws + WS_O);
    k5_outproj<<<dim3(64, 8), 256, 0, stream>>>(ws + WS_O, Po, ws + WS_YP);
    k5r_yreduce<<<YSLOT / 256, 256, 0, stream>>>(ws + WS_YP, out + OUT_Y);
}

// Round 9
// 253.322 us; speedup vs baseline: 1.1351x; 1.0779x over previous
//
#include <hip/hip_runtime.h>
#include <math.h>

#define Bb 64
#define Dd 4096
#define Hh 32
#define Kk 128
#define Vv 128
#define Mm 4096
#define MC 4097
#define NCH 16           // flash m-chunks (256 m each)
#define NSLOT 17         // 16 chunks + new-token slot

// workspace layout (float offsets)
#define WS_K1P  0                              // k1 partials: 34*16*8192
#define WS_Q    4456448                        // 262144
#define WS_NEWK (WS_Q + Bb*Hh*Kk)
#define WS_NEWV (WS_NEWK + Bb*Kk)
#define WS_PM   (WS_NEWV + Bb*Vv)              // 64*17*32
#define WS_PL   (WS_PM + Bb*NSLOT*Hh)
#define WS_PO   (WS_PL + Bb*NSLOT*Hh)          // 64*17*32*128
#define WS_O    (WS_PO + Bb*NSLOT*Hh*Vv)       // 262144
#define WS_YP   (WS_O + Bb*Hh*Vv)              // 8*262144

#define YSLOT (Bb*Dd)

// d_out layout (float offsets): y, Kc, Vc
#define OUT_Y  0
#define OUT_KC (Bb*Dd)
#define OUT_VC (OUT_KC + Bb*MC*Kk)

// LDS-only barrier: does NOT drain vmcnt, so global stores stay in flight.
#define BAR_LGKM() do { \
    __builtin_amdgcn_sched_barrier(0); \
    asm volatile("s_waitcnt lgkmcnt(0)" ::: "memory"); \
    __builtin_amdgcn_s_barrier(); \
    __builtin_amdgcn_sched_barrier(0); \
} while (0)

// ---------------- K1A: partial projections over d-chunk of 256
__global__ __launch_bounds__(256) void k1A_proj(const float* __restrict__ x,
        const float* __restrict__ Pq, const float* __restrict__ Pk,
        const float* __restrict__ Pv, float* __restrict__ part) {
    const int hidx = blockIdx.x;
    const int d0c  = blockIdx.y * 256;
    const int t = threadIdx.x;
    const int kg = t & 15, bg = t >> 4;
    const int kd = kg * 4, b0 = bg * 4;

    const float* P;
    if (hidx < Hh)       P = Pq + (size_t)hidx * Dd * Kk;
    else if (hidx == Hh) P = Pk;
    else                 P = Pv;

    __shared__ float xs[32 * 65];
    __shared__ float ps[32 * 128];

    float acc[4][8];
    #pragma unroll
    for (int a = 0; a < 4; a++)
        #pragma unroll
        for (int c = 0; c < 8; c++) acc[a][c] = 0.f;

    for (int tt = 0; tt < 8; tt++) {
        const int d0 = d0c + tt * 32;
        #pragma unroll
        for (int ii = 0; ii < 8; ii++) {
            int f = ii * 256 + t;
            int i = f & 31, bb = f >> 5;
            xs[i * 65 + bb] = x[(size_t)bb * Dd + d0 + i];
        }
        #pragma unroll
        for (int ii = 0; ii < 4; ii++) {
            int f = ii * 256 + t;
            int i = f >> 5, k4 = (f & 31) * 4;
            *(float4*)&ps[i * 128 + k4] = *(const float4*)&P[(size_t)(d0 + i) * Kk + k4];
        }
        __syncthreads();
        #pragma unroll
        for (int i = 0; i < 32; i++) {
            float xb[4];
            #pragma unroll
            for (int a = 0; a < 4; a++) xb[a] = xs[i * 65 + b0 + a];
            float4 p0 = *(float4*)&ps[i * 128 + kd];
            float4 p1 = *(float4*)&ps[i * 128 + 64 + kd];
            float pp[8] = {p0.x, p0.y, p0.z, p0.w, p1.x, p1.y, p1.z, p1.w};
            #pragma unroll
            for (int a = 0; a < 4; a++)
                #pragma unroll
                for (int c = 0; c < 8; c++)
                    acc[a][c] = fmaf(xb[a], pp[c], acc[a][c]);
        }
        __syncthreads();
    }
    float* dst = part + ((size_t)hidx * 16 + blockIdx.y) * 8192;
    #pragma unroll
    for (int a = 0; a < 4; a++) {
        int b = b0 + a;
        *(float4*)&dst[b * 128 + kd]      = make_float4(acc[a][0], acc[a][1], acc[a][2], acc[a][3]);
        *(float4*)&dst[b * 128 + 64 + kd] = make_float4(acc[a][4], acc[a][5], acc[a][6], acc[a][7]);
    }
}

// ---------------- K1B: reduce 16 chunks -> q / new_k / new_v
__global__ __launch_bounds__(256) void k1B_reduce(const float* __restrict__ part,
        float* __restrict__ ws) {
    const int o = blockIdx.x * 256 + threadIdx.x;
    const int hidx = o >> 13;
    const int rest = o & 8191;
    float s = 0.f;
    #pragma unroll
    for (int c = 0; c < 16; c++) s += part[((size_t)hidx * 16 + c) * 8192 + rest];
    if (hidx < Hh) {
        int b = rest >> 7, k = rest & 127;
        ws[WS_Q + ((size_t)b * Hh + hidx) * Kk + k] = s;
    } else if (hidx == Hh) {
        ws[WS_NEWK + rest] = s;
    } else {
        ws[WS_NEWV + rest] = s;
    }
}

// ---------------- KFLASH v7: fused copy + flash attention.
// New decomposition: QK k-split-2 with 4h x 4m register tiles (2 B/FMA),
// PV 4h x 4v tiles (2 B/FMA). scb combines k-partials; als broadcasts alpha.
// Roles: stage (kq,mKl,vq,mVl) / QK (kg,mg,hq) / PV (hq,vg).
__global__ __launch_bounds__(256) void kflash(const float* __restrict__ prevK,
        const float* __restrict__ prevV, const float* __restrict__ wq,
        float* __restrict__ outKc, float* __restrict__ outVc,
        float* __restrict__ PM, float* __restrict__ PL, float* __restrict__ PO) {
    const int c = blockIdx.x;      // 0..15
    const int b = blockIdx.y;
    const int t = threadIdx.x;
    // stage roles (v2-verified)
    const int kq = t & 15, mKl = t >> 4;
    const int vq = t & 31, mVl = t >> 5;
    // QK/softmax roles
    const int kg = t & 1;
    const int mg = (t >> 1) & 15;
    const int hq = t >> 5;          // 0..7 (also PV h-group)
    // PV roles
    const int vg = t & 31;

    __shared__ float ks_t[64 * 64];   // [k_half][m], ring-swizzled (16 KB)
    __shared__ float vs[32 * 132];    // [m_half][v] (16.9 KB)
    __shared__ float qs[128 * 36];    // [k][h] transposed, b128-by-4h (18.4 KB)
    __shared__ float wl[64 * 36];     // [m][h], b128-by-4h (9.2 KB)
    __shared__ float scb[32 * 64];    // k-split partial s (8 KB)
    __shared__ float als[32];         // per-h alpha

    // ---- stage q once (block-wide): 32h x 128k, transposed
    {
        const int h = t >> 3, kc = t & 7;
        const float* qr = wq + ((size_t)b * Hh + h) * Kk + kc * 16;
        float4 a0 = *(const float4*)&qr[0];
        float4 a1 = *(const float4*)&qr[4];
        float4 a2 = *(const float4*)&qr[8];
        float4 a3 = *(const float4*)&qr[12];
        const int k0 = kc * 16;
        qs[(k0+ 0)*36 + h] = a0.x; qs[(k0+ 1)*36 + h] = a0.y;
        qs[(k0+ 2)*36 + h] = a0.z; qs[(k0+ 3)*36 + h] = a0.w;
        qs[(k0+ 4)*36 + h] = a1.x; qs[(k0+ 5)*36 + h] = a1.y;
        qs[(k0+ 6)*36 + h] = a1.z; qs[(k0+ 7)*36 + h] = a1.w;
        qs[(k0+ 8)*36 + h] = a2.x; qs[(k0+ 9)*36 + h] = a2.y;
        qs[(k0+10)*36 + h] = a2.z; qs[(k0+11)*36 + h] = a2.w;
        qs[(k0+12)*36 + h] = a3.x; qs[(k0+13)*36 + h] = a3.y;
        qs[(k0+14)*36 + h] = a3.z; qs[(k0+15)*36 + h] = a3.w;
    }

    float rm[4] = {-3.0e38f, -3.0e38f, -3.0e38f, -3.0e38f};
    float rl[4] = {0.f, 0.f, 0.f, 0.f};
    float acc[4][4];
    #pragma unroll
    for (int a = 0; a < 4; a++)
        #pragma unroll
        for (int cc = 0; cc < 4; cc++) acc[a][cc] = 0.f;

    for (int st = 0; st < 4; st++) {
        const int m0 = c * 256 + st * 64;
        BAR_LGKM();                               // S1: prior subtile readers done
        // ---- global loads (blocking)
        float4 ka[8], va[8];
        #pragma unroll
        for (int ii = 0; ii < 4; ii++) {
            int mm = mKl + ii * 16;
            const float* src = prevK + ((size_t)b * Mm + m0 + mm) * Kk + kq * 4;
            ka[ii]     = *(const float4*)src;
            ka[ii + 4] = *(const float4*)(src + 64);
        }
        #pragma unroll
        for (int ii = 0; ii < 8; ii++) {
            int mm = mVl + ii * 8;
            va[ii] = *(const float4*)(prevV + ((size_t)b * Mm + m0 + mm) * Vv + vq * 4);
        }
        // ---- stage V half A (m 0..31) + K half0 (k 0..63)
        #pragma unroll
        for (int ii = 0; ii < 4; ii++)
            *(float4*)&vs[(mVl + ii * 8) * 132 + vq * 4] = va[ii];
        #pragma unroll
        for (int ii = 0; ii < 4; ii++) {
            int mm = mKl + ii * 16;
            int cs = (mm + 4 * kq) & 63;
            ks_t[(kq*4+0)*64 + cs] = ka[ii].x;
            ks_t[(kq*4+1)*64 + cs] = ka[ii].y;
            ks_t[(kq*4+2)*64 + cs] = ka[ii].z;
            ks_t[(kq*4+3)*64 + cs] = ka[ii].w;
        }
        // ---- Kc/Vc write-through (drains across raw barriers)
        #pragma unroll
        for (int ii = 0; ii < 4; ii++) {
            int mm = mKl + ii * 16;
            float* dK = outKc + ((size_t)b * MC + m0 + mm) * Kk + kq * 4;
            *(float4*)dK        = ka[ii];
            *(float4*)(dK + 64) = ka[ii + 4];
        }
        #pragma unroll
        for (int ii = 0; ii < 8; ii++) {
            int mm = mVl + ii * 8;
            *(float4*)(outVc + ((size_t)b * MC + m0 + mm) * Vv + vq * 4) = va[ii];
        }
        BAR_LGKM();                               // S2: vsA + ks0 visible
        float s[4][4];
        #pragma unroll
        for (int a = 0; a < 4; a++)
            #pragma unroll
            for (int cc = 0; cc < 4; cc++) s[a][cc] = 0.f;
        // ---- QK half0: k = kg*32 + j, j 0..31 (global k = rk)
        #pragma unroll 8
        for (int j = 0; j < 32; j++) {
            int rk = kg * 32 + j;
            float4 q4 = *(float4*)&qs[rk * 36 + hq * 4];
            int kc = (mg * 4 + 4 * (rk >> 2)) & 63;
            float4 k4 = *(float4*)&ks_t[rk * 64 + kc];
            #pragma unroll
            for (int a = 0; a < 4; a++) {
                float qa = (a==0)?q4.x:(a==1)?q4.y:(a==2)?q4.z:q4.w;
                s[a][0] = fmaf(qa, k4.x, s[a][0]);
                s[a][1] = fmaf(qa, k4.y, s[a][1]);
                s[a][2] = fmaf(qa, k4.z, s[a][2]);
                s[a][3] = fmaf(qa, k4.w, s[a][3]);
            }
        }
        BAR_LGKM();                               // S3: ks0 reads done
        #pragma unroll
        for (int ii = 0; ii < 4; ii++) {          // stage K half1 (k 64..127)
            int mm = mKl + ii * 16;
            int cs = (mm + 4 * kq) & 63;
            ks_t[(kq*4+0)*64 + cs] = ka[ii+4].x;
            ks_t[(kq*4+1)*64 + cs] = ka[ii+4].y;
            ks_t[(kq*4+2)*64 + cs] = ka[ii+4].z;
            ks_t[(kq*4+3)*64 + cs] = ka[ii+4].w;
        }
        BAR_LGKM();                               // S4: ks1 visible
        // ---- QK half1
        #pragma unroll 8
        for (int j = 0; j < 32; j++) {
            int rk = kg * 32 + j;
            float4 q4 = *(float4*)&qs[(64 + rk) * 36 + hq * 4];
            int kc = (mg * 4 + 4 * (rk >> 2)) & 63;
            float4 k4 = *(float4*)&ks_t[rk * 64 + kc];
            #pragma unroll
            for (int a = 0; a < 4; a++) {
                float qa = (a==0)?q4.x:(a==1)?q4.y:(a==2)?q4.z:q4.w;
                s[a][0] = fmaf(qa, k4.x, s[a][0]);
                s[a][1] = fmaf(qa, k4.y, s[a][1]);
                s[a][2] = fmaf(qa, k4.z, s[a][2]);
                s[a][3] = fmaf(qa, k4.w, s[a][3]);
            }
        }
        // ---- combine k-split partials: kg1 writes, kg0 sums
        if (kg) {
            #pragma unroll
            for (int a = 0; a < 4; a++)
                *(float4*)&scb[(hq*4 + a) * 64 + mg * 4] =
                    make_float4(s[a][0], s[a][1], s[a][2], s[a][3]);
        }
        BAR_LGKM();                               // S5: scb visible
        if (!kg) {
            #pragma unroll
            for (int a = 0; a < 4; a++) {
                float4 pp = *(float4*)&scb[(hq*4 + a) * 64 + mg * 4];
                s[a][0] += pp.x; s[a][1] += pp.y; s[a][2] += pp.z; s[a][3] += pp.w;
            }
        }
        // ---- softmax (kg0 threads own rows; reduce over mg lanes)
        float p[4][4];
        float al4[4];
        #pragma unroll
        for (int a = 0; a < 4; a++) {
            float mloc = fmaxf(fmaxf(s[a][0], s[a][1]), fmaxf(s[a][2], s[a][3]));
            mloc = fmaxf(mloc, __shfl_xor(mloc, 2, 64));
            mloc = fmaxf(mloc, __shfl_xor(mloc, 4, 64));
            mloc = fmaxf(mloc, __shfl_xor(mloc, 8, 64));
            mloc = fmaxf(mloc, __shfl_xor(mloc, 16, 64));
            float nm = fmaxf(rm[a], mloc);
            al4[a] = __expf(rm[a] - nm);
            float psum = 0.f;
            #pragma unroll
            for (int cc = 0; cc < 4; cc++) {
                p[a][cc] = __expf(s[a][cc] - nm);
                psum += p[a][cc];
            }
            psum += __shfl_xor(psum, 2, 64);
            psum += __shfl_xor(psum, 4, 64);
            psum += __shfl_xor(psum, 8, 64);
            psum += __shfl_xor(psum, 16, 64);
            rl[a] = rl[a] * al4[a] + psum;
            rm[a] = nm;
        }
        if (!kg) {
            #pragma unroll
            for (int cc = 0; cc < 4; cc++)
                *(float4*)&wl[(mg*4 + cc) * 36 + hq * 4] =
                    make_float4(p[0][cc], p[1][cc], p[2][cc], p[3][cc]);
            if (mg == 0) {
                #pragma unroll
                for (int a = 0; a < 4; a++) als[hq*4 + a] = al4[a];
            }
        }
        BAR_LGKM();                               // S6: wl + als visible
        // ---- PV: rescale then phase A (m 0..31)
        {
            float4 a4 = *(float4*)&als[hq * 4];
            float aa[4] = {a4.x, a4.y, a4.z, a4.w};
            #pragma unroll
            for (int a = 0; a < 4; a++)
                #pragma unroll
                for (int cc = 0; cc < 4; cc++) acc[a][cc] *= aa[a];
        }
        #pragma unroll 8
        for (int m = 0; m < 32; m++) {
            float4 w4 = *(float4*)&wl[m * 36 + hq * 4];
            float4 v4 = *(float4*)&vs[m * 132 + vg * 4];
            #pragma unroll
            for (int a = 0; a < 4; a++) {
                float wa = (a==0)?w4.x:(a==1)?w4.y:(a==2)?w4.z:w4.w;
                acc[a][0] = fmaf(wa, v4.x, acc[a][0]);
                acc[a][1] = fmaf(wa, v4.y, acc[a][1]);
                acc[a][2] = fmaf(wa, v4.z, acc[a][2]);
                acc[a][3] = fmaf(wa, v4.w, acc[a][3]);
            }
        }
        BAR_LGKM();                               // S7: vsA reads done
        #pragma unroll
        for (int ii = 0; ii < 4; ii++)            // stage V half B (m 32..63)
            *(float4*)&vs[(mVl + ii * 8) * 132 + vq * 4] = va[ii + 4];
        BAR_LGKM();                               // S8: vsB visible
        #pragma unroll 8
        for (int m = 0; m < 32; m++) {
            float4 w4 = *(float4*)&wl[(32 + m) * 36 + hq * 4];
            float4 v4 = *(float4*)&vs[m * 132 + vg * 4];
            #pragma unroll
            for (int a = 0; a < 4; a++) {
                float wa = (a==0)?w4.x:(a==1)?w4.y:(a==2)?w4.z:w4.w;
                acc[a][0] = fmaf(wa, v4.x, acc[a][0]);
                acc[a][1] = fmaf(wa, v4.y, acc[a][1]);
                acc[a][2] = fmaf(wa, v4.z, acc[a][2]);
                acc[a][3] = fmaf(wa, v4.w, acc[a][3]);
            }
        }
    }
    // ---- write partials
    const size_t base = ((size_t)b * NSLOT + c) * Hh;
    if (kg == 0 && mg == 0) {
        #pragma unroll
        for (int a = 0; a < 4; a++) {
            PM[base + hq*4 + a] = rm[a];
            PL[base + hq*4 + a] = rl[a];
        }
    }
    #pragma unroll
    for (int a = 0; a < 4; a++)
        *(float4*)&PO[(base + hq*4 + a) * Vv + vg * 4] =
            make_float4(acc[a][0], acc[a][1], acc[a][2], acc[a][3]);
}

// ---------------- KNEW: new-token slot NCH partial + Kc/Vc row 4096
__global__ __launch_bounds__(128) void knew(const float* __restrict__ ws,
        float* __restrict__ outKc, float* __restrict__ outVc,
        float* __restrict__ PM, float* __restrict__ PL, float* __restrict__ PO) {
    const int b = blockIdx.x, t = threadIdx.x;
    const float* q    = ws + WS_Q;
    const float* newk = ws + WS_NEWK;
    const float* newv = ws + WS_NEWV;
    const int h = t >> 2, j = t & 3;
    const float* qr = q + ((size_t)b * Hh + h) * Kk + j * 32;
    const float* nk = newk + (size_t)b * Kk + j * 32;
    float s0 = 0.f, s1 = 0.f, s2 = 0.f, s3 = 0.f;
    #pragma unroll
    for (int i = 0; i < 8; i++) {
        float4 a  = *(const float4*)&qr[i * 4];
        float4 c4 = *(const float4*)&nk[i * 4];
        s0 = fmaf(a.x, c4.x, s0); s1 = fmaf(a.y, c4.y, s1);
        s2 = fmaf(a.z, c4.z, s2); s3 = fmaf(a.w, c4.w, s3);
    }
    float s = (s0 + s1) + (s2 + s3);
    s += __shfl_xor(s, 1, 64);
    s += __shfl_xor(s, 2, 64);
    const size_t base = ((size_t)b * NSLOT + NCH) * Hh;
    if (j == 0) { PM[base + h] = s; PL[base + h] = 1.f; }
    float nv = newv[(size_t)b * Vv + t];
    outKc[((size_t)b * MC + Mm) * Kk + t] = newk[(size_t)b * Kk + t];
    outVc[((size_t)b * MC + Mm) * Vv + t] = nv;
    #pragma unroll 4
    for (int hh = 0; hh < Hh; hh++)
        PO[(base + hh) * Vv + t] = nv;
}

// ---------------- KCOMB: merge NSLOT partial slots -> O[b,h,v]
__global__ __launch_bounds__(128) void kcomb(const float* __restrict__ PM,
        const float* __restrict__ PL, const float* __restrict__ PO,
        float* __restrict__ O) {
    const int h = blockIdx.x, b = blockIdx.y, t = threadIdx.x;
    __shared__ float ml[NSLOT], ll[NSLOT];
    if (t < NSLOT) {
        ml[t] = PM[((size_t)b * NSLOT + t) * Hh + h];
        ll[t] = PL[((size_t)b * NSLOT + t) * Hh + h];
    }
    __syncthreads();
    float M = -3.0e38f;
    #pragma unroll
    for (int c = 0; c < NSLOT; c++) M = fmaxf(M, ml[c]);
    float L = 0.f, o = 0.f;
    #pragma unroll
    for (int c = 0; c < NSLOT; c++) {
        float e = __expf(ml[c] - M);
        L += ll[c] * e;
        o = fmaf(e, PO[(((size_t)b * NSLOT + c) * Hh + h) * Vv + t], o);
    }
    O[((size_t)b * Hh + h) * Vv + t] = o / L;
}

// ---------------- K5: y_part[hq][b,d] = sum_{h in quad, v} O[b,h,v] * P_o[h,d,v]
__global__ __launch_bounds__(256) void k5_outproj(const float* __restrict__ O,
        const float* __restrict__ Po, float* __restrict__ ypart) {
    const int dbase = blockIdx.x * 64;
    const int hq = blockIdx.y;
    const int t = threadIdx.x;
    __shared__ float os[64 * 64];   // [b][v-half], ring-swizzled
    __shared__ float ps2[64 * 64];  // [d][v-half], ring-swizzled
    const int dg = t & 15, bg = t >> 4;
    const int d0 = dg * 4, b0 = bg * 4;
    float acc[4][4] = {};
    for (int hi = 0; hi < 4; hi++) {
        const int h = hq * 4 + hi;
        for (int vh = 0; vh < 2; vh++) {
            __syncthreads();
            #pragma unroll
            for (int ii = 0; ii < 4; ii++) {
                int f = ii * 256 + t;
                int vq2 = f & 15, r = f >> 4;
                int colp = (4 * vq2 + 4 * (r >> 2)) & 63;
                *(float4*)&os[r * 64 + colp] =
                    *(const float4*)&O[((size_t)(r * Hh + h)) * Vv + vh * 64 + 4 * vq2];
                *(float4*)&ps2[r * 64 + colp] =
                    *(const float4*)&Po[((size_t)h * Dd + dbase + r) * Vv + vh * 64 + 4 * vq2];
            }
            __syncthreads();
            #pragma unroll
            for (int v4 = 0; v4 < 16; v4++) {
                float4 pd[4], ob[4];
                #pragma unroll
                for (int cc = 0; cc < 4; cc++)
                    pd[cc] = *(float4*)&ps2[(d0 + cc) * 64 + ((4*v4 + 4*dg) & 63)];
                #pragma unroll
                for (int a = 0; a < 4; a++)
                    ob[a] = *(float4*)&os[(b0 + a) * 64 + ((4*v4 + 4*bg) & 63)];
                #pragma unroll
                for (int a = 0; a < 4; a++)
                    #pragma unroll
                    for (int cc = 0; cc < 4; cc++) {
                        acc[a][cc] = fmaf(ob[a].x, pd[cc].x, acc[a][cc]);
                        acc[a][cc] = fmaf(ob[a].y, pd[cc].y, acc[a][cc]);
                        acc[a][cc] = fmaf(ob[a].z, pd[cc].z, acc[a][cc]);
                        acc[a][cc] = fmaf(ob[a].w, pd[cc].w, acc[a][cc]);
                    }
            }
        }
    }
    float* yp = ypart + (size_t)hq * YSLOT;
    #pragma unroll
    for (int a = 0; a < 4; a++)
        *(float4*)&yp[(size_t)(b0 + a) * Dd + dbase + d0] =
            make_float4(acc[a][0], acc[a][1], acc[a][2], acc[a][3]);
}

// ---------------- K5r: y = sum of 8 y-partial slots
__global__ __launch_bounds__(256) void k5r_yreduce(const float* __restrict__ ypart,
        float* __restrict__ y) {
    const int o = blockIdx.x * 256 + threadIdx.x;
    float s = 0.f;
    #pragma unroll
    for (int c = 0; c < 8; c++) s += ypart[(size_t)c * YSLOT + o];
    y[o] = s;
}

extern "C" void kernel_launch(void* const* d_in, const int* in_sizes, int n_in,
                              void* d_out, int out_size, void* d_ws, size_t ws_size,
                              hipStream_t stream) {
    const float* x     = (const float*)d_in[0];
    const float* prevK = (const float*)d_in[1];
    const float* prevV = (const float*)d_in[2];
    const float* Pq    = (const float*)d_in[3];
    const float* Pk    = (const float*)d_in[4];
    const float* Pv    = (const float*)d_in[5];
    const float* Po    = (const float*)d_in[6];
    float* out = (float*)d_out;
    float* ws  = (float*)d_ws;

    k1A_proj<<<dim3(Hh + 2, 16), 256, 0, stream>>>(x, Pq, Pk, Pv, ws + WS_K1P);
    k1B_reduce<<<(34 * 8192) / 256, 256, 0, stream>>>(ws + WS_K1P, ws);
    kflash<<<dim3(NCH, Bb), 256, 0, stream>>>(prevK, prevV, ws + WS_Q,
                                              out + OUT_KC, out + OUT_VC,
                                              ws + WS_PM, ws + WS_PL, ws + WS_PO);
    knew<<<Bb, 128, 0, stream>>>(ws, out + OUT_KC, out + OUT_VC,
                                 ws + WS_PM, ws + WS_PL, ws + WS_PO);
    kcomb<<<dim3(Hh, Bb), 128, 0, stream>>>(ws + WS_PM, ws + WS_PL, ws + WS_PO,
                                            ws + WS_O);
    k5_outproj<<<dim3(64, 8), 256, 0, stream>>>(ws + WS_O, Po, ws + WS_YP);
    k5r_yreduce<<<YSLOT / 256, 256, 0, stream>>>(ws + WS_YP, out + OUT_Y);
}